// Round 12
// baseline (9505.177 us; speedup 1.0000x reference)
//
#include <hip/hip_runtime.h>
#include <stdint.h>

#define TT 512
#define BB 64
#define II 256
#define HS 512          // H
#define HHALF 256       // HH
#define R4H 2048        // 4*H
#define HB_STRIDE 16384 // 64 batches * 256 unit-pair words per h buffer

typedef __attribute__((ext_vector_type(8))) short short8v;  // 8 bf16 = 4 VGPR
typedef __attribute__((ext_vector_type(4))) float f32x4;

// ---------------------------------------------------------------------------
// Phase 1: PG[t][r][b] = (b_ih[r]+b_hh[r]) + sum_k W_ih[r][k] * X[b][t][k]
// ---------------------------------------------------------------------------
__global__ __launch_bounds__(256) void pregemm(
    const float* __restrict__ X,    // [B][T][I]
    const float* __restrict__ Wih,  // [4H][I]
    const float* __restrict__ bih,
    const float* __restrict__ bhh,
    float* __restrict__ PG)         // [T][4H][B]
{
  __shared__ __align__(16) float Xs[64][68];
  __shared__ __align__(16) float Ws[64][68];
  const int t = blockIdx.x;
  const int rbase = blockIdx.y * 64;
  const int tid = threadIdx.x;
  const int cg = tid & 15;
  const int rg = tid >> 4;

  float acc[4][4] = {};

  for (int k0 = 0; k0 < II; k0 += 64) {
    {
      int b = tid >> 2, kq = tid & 3;
      const float* src = X + ((size_t)b * TT + t) * II + k0 + kq * 16;
      #pragma unroll
      for (int i = 0; i < 16; i += 4) {
        float4 v = *(const float4*)(src + i);
        int kk = kq * 16 + i;
        Xs[kk + 0][b] = v.x; Xs[kk + 1][b] = v.y;
        Xs[kk + 2][b] = v.z; Xs[kk + 3][b] = v.w;
      }
    }
    {
      int r = tid >> 2, kq = tid & 3;
      const float* src = Wih + (size_t)(rbase + r) * II + k0 + kq * 16;
      #pragma unroll
      for (int i = 0; i < 16; i += 4) {
        float4 v = *(const float4*)(src + i);
        int kk = kq * 16 + i;
        Ws[kk + 0][r] = v.x; Ws[kk + 1][r] = v.y;
        Ws[kk + 2][r] = v.z; Ws[kk + 3][r] = v.w;
      }
    }
    __syncthreads();
    #pragma unroll 8
    for (int kk = 0; kk < 64; ++kk) {
      float4 a = *(const float4*)&Ws[kk][rg * 4];
      float4 x = *(const float4*)&Xs[kk][cg * 4];
      float av[4] = {a.x, a.y, a.z, a.w};
      float xv[4] = {x.x, x.y, x.z, x.w};
      #pragma unroll
      for (int i = 0; i < 4; ++i)
        #pragma unroll
        for (int j = 0; j < 4; ++j)
          acc[i][j] = fmaf(av[i], xv[j], acc[i][j]);
    }
    __syncthreads();
  }

  #pragma unroll
  for (int i = 0; i < 4; ++i) {
    int row = rbase + rg * 4 + i;
    float bias = bih[row] + bhh[row];
    float4 o;
    o.x = acc[i][0] + bias; o.y = acc[i][1] + bias;
    o.z = acc[i][2] + bias; o.w = acc[i][3] + bias;
    *(float4*)&PG[((size_t)t * R4H + row) * BB + cg * 4] = o;
  }
}

// ---------------------------------------------------------------------------
__device__ __forceinline__ uint32_t bf16r(float f) {
  uint32_t u = __float_as_uint(f);
  u += 0x7fffu + ((u >> 16) & 1u);
  return u >> 16;
}

// init: hbT[0][b][uh] = pack(bf16(h[2uh]), bf16(h[2uh+1]))  (layout [64][256])
__global__ void init_h(const float* __restrict__ mem, uint32_t* __restrict__ hb)
{
  int idx = blockIdx.x * 256 + threadIdx.x;
  if (idx < HB_STRIDE) {
    int b = idx >> 8, uh = idx & 255;
    float lo = mem[(size_t)b * 1280 + 256 + 2 * uh];
    float hi = mem[(size_t)b * 1280 + 256 + 2 * uh + 1];
    hb[idx] = bf16r(lo) | (bf16r(hi) << 16);
  }
}

// ---------------------------------------------------------------------------
// Cross-XCD h hand-off (proven R6): relaxed agent-scope EXCHANGE stores (RMW
// performed at the IF coherence point; vmcnt(0) ack => globally visible) +
// relaxed agent-scope loads (bypass stale L1/L2). No wbl2/inv sweeps.
// ---------------------------------------------------------------------------
__device__ __forceinline__ void store_coh_u32(uint32_t* p, uint32_t v) {
  (void)__hip_atomic_exchange(p, v, __ATOMIC_RELAXED, __HIP_MEMORY_SCOPE_AGENT);
}
__device__ __forceinline__ uint32_t load_coh_u32(const uint32_t* p) {
  return __hip_atomic_load(p, __ATOMIC_RELAXED, __HIP_MEMORY_SCOPE_AGENT);
}

// gsum addressing: 2-way-max bank pattern via XOR of bit4 with (row>>2)&1
#define GIDX(row, col) (((row) << 6) + ((col) ^ ((((row) >> 2) & 1) << 4)))

// ---------------------------------------------------------------------------
// Persistent LSTM, MFMA edition (R12). grid = 32 WGs x 512 threads.
// WG g owns units [g*16, g*16+16), ALL 64 batches. Per step:
//   gates[64 rows][64 b] = sum_k W_bf16 x h_bf16 via mfma_f32_16x16x32_bf16.
// Wave wu: batch-tile bt=wu>>1, row-tile pair rtp=wu&1 (rt = 2rtp, 2rtp+1).
// W (bf16) preloaded in VGPRs once (128 VGPR) -> zero per-step W traffic.
// h stored TRANSPOSED hbT[b][u/2] so a B-frag = 4 consecutive u32 per lane.
// Fragment layouts (gfx950 16x16x32 bf16): A row=l&15, k=(l>>4)*8+j;
// B col=l&15, k=(l>>4)*8+j; D col=l&15, row=(l>>4)*4+reg [m89-verified].
// Sync: single 32-arrival monotonic counter, relaxed agent RMWs (proven).
// ---------------------------------------------------------------------------
__global__ __launch_bounds__(512, 2) void lstm_persistent(
    const float* __restrict__ mem,   // [B][1280]
    const float* __restrict__ Whh,   // [4H][H] f32
    float* __restrict__ PG,          // [T][4H][B]
    uint32_t* __restrict__ hb,       // [2][64][256] packed bf16x2, transposed
    float* __restrict__ outmem,      // [B][1280]
    unsigned* __restrict__ bar)      // cnt@0, gen@64
{
  __shared__ float gsum[64 * 64];    // 16 KB

  const int g    = blockIdx.x;       // 0..31
  const int tid  = threadIdx.x;
  const int wu   = tid >> 6;         // wave 0..7
  const int lane = tid & 63;
  const int l15  = lane & 15;
  const int lq   = lane >> 4;        // 0..3
  const int bt   = wu >> 1;          // batch tile 0..3
  const int rtp  = wu & 1;           // row-tile pair 0..1
  const int u0   = g * 16;

  unsigned* cnt = bar;
  unsigned* gen = bar + 64;

  // ---- A preload: W slice -> bf16 VGPR fragments (once) ----
  short8v aF0[16], aF1[16];
  {
    const float* w0p = Whh + (size_t)((rtp * 2 + 0) * HS + u0 + l15) * HS + lq * 8;
    const float* w1p = Whh + (size_t)((rtp * 2 + 1) * HS + u0 + l15) * HS + lq * 8;
    #pragma unroll
    for (int ks = 0; ks < 16; ++ks) {
      float4 x0 = *(const float4*)(w0p + ks * 32);
      float4 x1 = *(const float4*)(w0p + ks * 32 + 4);
      union { uint32_t u[4]; short8v v; } cv;
      cv.u[0] = bf16r(x0.x) | (bf16r(x0.y) << 16);
      cv.u[1] = bf16r(x0.z) | (bf16r(x0.w) << 16);
      cv.u[2] = bf16r(x1.x) | (bf16r(x1.y) << 16);
      cv.u[3] = bf16r(x1.z) | (bf16r(x1.w) << 16);
      aF0[ks] = cv.v;
      float4 y0 = *(const float4*)(w1p + ks * 32);
      float4 y1 = *(const float4*)(w1p + ks * 32 + 4);
      union { uint32_t u[4]; short8v v; } cw;
      cw.u[0] = bf16r(y0.x) | (bf16r(y0.y) << 16);
      cw.u[1] = bf16r(y0.z) | (bf16r(y0.w) << 16);
      cw.u[2] = bf16r(y1.x) | (bf16r(y1.y) << 16);
      cw.u[3] = bf16r(y1.z) | (bf16r(y1.w) << 16);
      aF1[ks] = cw.v;
    }
  }

  // ---- elementwise state: thread = (unit-pair p = wu, batch eb = lane) ----
  const int p = wu, eb = lane;
  float c0 = mem[(size_t)eb * 1280 + 768 + u0 + 2 * p];
  float c1 = mem[(size_t)eb * 1280 + 768 + u0 + 2 * p + 1];
  float m0 = 0.f, m1 = 0.f, h0l = 0.f, h1l = 0.f;
  if (u0 < HHALF) {
    m0 = mem[(size_t)eb * 1280 + u0 + 2 * p];
    m1 = mem[(size_t)eb * 1280 + u0 + 2 * p + 1];
  }

  // ---- pg prefetch for t=0 (2 tiles x 4 regs per lane) ----
  float pgA[4], pgB[4];
  #pragma unroll
  for (int r = 0; r < 4; ++r) {
    pgA[r] = PG[((size_t)0 * R4H + (rtp * 2 + 0) * HS + u0 + lq * 4 + r) * BB + bt * 16 + l15];
    pgB[r] = PG[((size_t)0 * R4H + (rtp * 2 + 1) * HS + u0 + lq * 4 + r) * BB + bt * 16 + l15];
  }

  for (int t = 0; t < TT; ++t) {
    // ---- B-frag loads (coherent) + MFMA over K=512 ----
    f32x4 acc0 = {0.f, 0.f, 0.f, 0.f}, acc1 = {0.f, 0.f, 0.f, 0.f};
    const uint32_t* hT = hb + (size_t)(t & 1) * HB_STRIDE
                            + (size_t)(bt * 16 + l15) * 256 + lq * 4;
    #pragma unroll
    for (int ks = 0; ks < 16; ++ks) {
      union { uint32_t u[4]; short8v v; } bf;
      #pragma unroll
      for (int m = 0; m < 4; ++m) bf.u[m] = load_coh_u32(hT + ks * 16 + m);
      acc0 = __builtin_amdgcn_mfma_f32_16x16x32_bf16(aF0[ks], bf.v, acc0, 0, 0, 0);
      acc1 = __builtin_amdgcn_mfma_f32_16x16x32_bf16(aF1[ks], bf.v, acc1, 0, 0, 0);
    }

    // ---- add pre-gates, write to gsum (2-way-max banks) ----
    {
      const int colw = bt * 16 + l15;
      #pragma unroll
      for (int r = 0; r < 4; ++r) {
        int row0 = (rtp * 2 + 0) * 16 + lq * 4 + r;
        int row1 = (rtp * 2 + 1) * 16 + lq * 4 + r;
        gsum[GIDX(row0, colw)] = acc0[r] + pgA[r];
        gsum[GIDX(row1, colw)] = acc1[r] + pgB[r];
      }
    }
    __syncthreads();

    // ---- elementwise: 2 cells (units u0+2p, u0+2p+1) x batch eb ----
    {
      const int ul0 = 2 * p, ul1 = 2 * p + 1;
      float gi0 = gsum[GIDX( 0 + ul0, eb)];
      float gf0 = gsum[GIDX(16 + ul0, eb)];
      float gg0 = gsum[GIDX(32 + ul0, eb)];
      float go0 = gsum[GIDX(48 + ul0, eb)];
      float gi1 = gsum[GIDX( 0 + ul1, eb)];
      float gf1 = gsum[GIDX(16 + ul1, eb)];
      float gg1 = gsum[GIDX(32 + ul1, eb)];
      float go1 = gsum[GIDX(48 + ul1, eb)];
      float si0 = 1.f / (1.f + __expf(-gi0));
      float sf0 = 1.f / (1.f + __expf(-gf0));
      float so0 = 1.f / (1.f + __expf(-go0));
      float si1 = 1.f / (1.f + __expf(-gi1));
      float sf1 = 1.f / (1.f + __expf(-gf1));
      float so1 = 1.f / (1.f + __expf(-go1));
      c0 = sf0 * c0 + si0 * tanhf(gg0);
      c1 = sf1 * c1 + si1 * tanhf(gg1);
      float h0 = so0 * tanhf(c0);
      float h1 = so1 * tanhf(c1);
      h0l = h0; h1l = h1;
      // transposed packed store: hbT[eb][g*8+p] (unit pair is thread-local)
      store_coh_u32(&hb[(size_t)((t + 1) & 1) * HB_STRIDE + (size_t)eb * 256 + g * 8 + p],
                    bf16r(h0) | (bf16r(h1) << 16));
      float out0 = h0, out1 = h1;
      if (u0 < HHALF) { m0 = fmaxf(m0, h0); m1 = fmaxf(m1, h1); out0 = m0; out1 = m1; }
      PG[((size_t)t * R4H + u0 + 2 * p) * BB + eb]     = out0;  // stash
      PG[((size_t)t * R4H + u0 + 2 * p + 1) * BB + eb] = out1;
    }

    // ---- barrier: release = vmcnt(0) on the exchange h-stores ----
    asm volatile("s_waitcnt vmcnt(0)" ::: "memory");
    __syncthreads();
    // pg prefetch for t+1 hides under the barrier
    if (t + 1 < TT) {
      #pragma unroll
      for (int r = 0; r < 4; ++r) {
        pgA[r] = PG[((size_t)(t + 1) * R4H + (rtp * 2 + 0) * HS + u0 + lq * 4 + r) * BB + bt * 16 + l15];
        pgB[r] = PG[((size_t)(t + 1) * R4H + (rtp * 2 + 1) * HS + u0 + lq * 4 + r) * BB + bt * 16 + l15];
      }
    }
    if (tid == 0) {
      unsigned a = __hip_atomic_fetch_add(cnt, 1u, __ATOMIC_RELAXED,
                                          __HIP_MEMORY_SCOPE_AGENT);
      if (a == 32u * (unsigned)(t + 1) - 1u)
        (void)__hip_atomic_exchange(gen, (unsigned)(t + 1), __ATOMIC_RELAXED,
                                    __HIP_MEMORY_SCOPE_AGENT);
      // failsafe cap: fast wrong-answer instead of a hang; expected wait ~us.
      int spins = 0;
      while (__hip_atomic_load(gen, __ATOMIC_RELAXED,
                               __HIP_MEMORY_SCOPE_AGENT) < (unsigned)(t + 1)) {
        __builtin_amdgcn_s_sleep(1);
        if (++spins > (1 << 16)) break;
      }
    }
    __syncthreads();
  }

  // ---- finals ----
  outmem[(size_t)eb * 1280 + 256 + u0 + 2 * p]     = h0l;
  outmem[(size_t)eb * 1280 + 256 + u0 + 2 * p + 1] = h1l;
  outmem[(size_t)eb * 1280 + 768 + u0 + 2 * p]     = c0;
  outmem[(size_t)eb * 1280 + 768 + u0 + 2 * p + 1] = c1;
  if (u0 < HHALF) {
    outmem[(size_t)eb * 1280 + u0 + 2 * p]     = m0;
    outmem[(size_t)eb * 1280 + u0 + 2 * p + 1] = m1;
  }
}

// ---------------------------------------------------------------------------
// Phase 3: out[b][t][u] = PG[t][u][b]  (u < 512)
// ---------------------------------------------------------------------------
__global__ __launch_bounds__(256) void transpose_out(
    const float* __restrict__ PG, float* __restrict__ out)
{
  __shared__ __align__(16) float tileS[64][68];
  const int t = blockIdx.x;
  const int u0 = blockIdx.y * 64;
  const int tid = threadIdx.x;

  {
    int cg = tid & 15, rg = tid >> 4;
    const float* src = PG + (size_t)t * R4H * BB + (size_t)u0 * BB;
    #pragma unroll
    for (int i = 0; i < 4; ++i) {
      int u = rg * 4 + i;
      float4 v = *(const float4*)(src + (size_t)u * BB + cg * 4);
      *(float4*)&tileS[u][cg * 4] = v;
    }
  }
  __syncthreads();
  {
    int ug = tid & 15, bg = tid >> 4;
    #pragma unroll
    for (int i = 0; i < 4; ++i) {
      int b = bg * 4 + i;
      float4 o;
      o.x = tileS[ug * 4 + 0][b];
      o.y = tileS[ug * 4 + 1][b];
      o.z = tileS[ug * 4 + 2][b];
      o.w = tileS[ug * 4 + 3][b];
      *(float4*)&out[((size_t)b * TT + t) * HS + u0 + ug * 4] = o;
    }
  }
}

// ---------------------------------------------------------------------------
extern "C" void kernel_launch(void* const* d_in, const int* in_sizes, int n_in,
                              void* d_out, int out_size, void* d_ws, size_t ws_size,
                              hipStream_t stream)
{
  const float* X   = (const float*)d_in[0];
  const float* mem = (const float*)d_in[1];
  const float* Wih = (const float*)d_in[2];
  const float* Whh = (const float*)d_in[3];
  const float* bih = (const float*)d_in[4];
  const float* bhh = (const float*)d_in[5];

  float* out = (float*)d_out;
  float* outmem = out + (size_t)BB * TT * HS;

  float* PG     = (float*)d_ws;                      // 512*2048*64 f32 = 256 MB
  uint32_t* hbp = (uint32_t*)(PG + (size_t)TT * R4H * BB);  // 2*16384 u32
  unsigned* bar = (unsigned*)(hbp + 2 * HB_STRIDE);  // 2048 u32

  hipMemsetAsync(bar, 0, 2048 * sizeof(unsigned), stream);
  init_h<<<dim3(HB_STRIDE / 256), dim3(256), 0, stream>>>(mem, hbp);
  pregemm<<<dim3(TT, 32), dim3(256), 0, stream>>>(X, Wih, bih, bhh, PG);
  lstm_persistent<<<dim3(32), dim3(512), 0, stream>>>(mem, Whh, PG, hbp, outmem, bar);
  transpose_out<<<dim3(TT, 8), dim3(256), 0, stream>>>(PG, out);
}

// Round 13
// 9501.624 us; speedup vs baseline: 1.0004x; 1.0004x over previous
//
#include <hip/hip_runtime.h>
#include <stdint.h>

#define TT 512
#define BB 64
#define II 256
#define HS 512          // H
#define HHALF 256       // HH
#define R4H 2048        // 4*H
#define HB_STRIDE 16384 // 64 batches * 256 unit-pair words per h buffer

typedef __attribute__((ext_vector_type(8))) short short8v;  // 8 bf16 = 4 VGPR
typedef __attribute__((ext_vector_type(4))) float f32x4;

// ---------------------------------------------------------------------------
// Phase 1: PG[t][r][b] = (b_ih[r]+b_hh[r]) + sum_k W_ih[r][k] * X[b][t][k]
// ---------------------------------------------------------------------------
__global__ __launch_bounds__(256) void pregemm(
    const float* __restrict__ X,    // [B][T][I]
    const float* __restrict__ Wih,  // [4H][I]
    const float* __restrict__ bih,
    const float* __restrict__ bhh,
    float* __restrict__ PG)         // [T][4H][B]
{
  __shared__ __align__(16) float Xs[64][68];
  __shared__ __align__(16) float Ws[64][68];
  const int t = blockIdx.x;
  const int rbase = blockIdx.y * 64;
  const int tid = threadIdx.x;
  const int cg = tid & 15;
  const int rg = tid >> 4;

  float acc[4][4] = {};

  for (int k0 = 0; k0 < II; k0 += 64) {
    {
      int b = tid >> 2, kq = tid & 3;
      const float* src = X + ((size_t)b * TT + t) * II + k0 + kq * 16;
      #pragma unroll
      for (int i = 0; i < 16; i += 4) {
        float4 v = *(const float4*)(src + i);
        int kk = kq * 16 + i;
        Xs[kk + 0][b] = v.x; Xs[kk + 1][b] = v.y;
        Xs[kk + 2][b] = v.z; Xs[kk + 3][b] = v.w;
      }
    }
    {
      int r = tid >> 2, kq = tid & 3;
      const float* src = Wih + (size_t)(rbase + r) * II + k0 + kq * 16;
      #pragma unroll
      for (int i = 0; i < 16; i += 4) {
        float4 v = *(const float4*)(src + i);
        int kk = kq * 16 + i;
        Ws[kk + 0][r] = v.x; Ws[kk + 1][r] = v.y;
        Ws[kk + 2][r] = v.z; Ws[kk + 3][r] = v.w;
      }
    }
    __syncthreads();
    #pragma unroll 8
    for (int kk = 0; kk < 64; ++kk) {
      float4 a = *(const float4*)&Ws[kk][rg * 4];
      float4 x = *(const float4*)&Xs[kk][cg * 4];
      float av[4] = {a.x, a.y, a.z, a.w};
      float xv[4] = {x.x, x.y, x.z, x.w};
      #pragma unroll
      for (int i = 0; i < 4; ++i)
        #pragma unroll
        for (int j = 0; j < 4; ++j)
          acc[i][j] = fmaf(av[i], xv[j], acc[i][j]);
    }
    __syncthreads();
  }

  #pragma unroll
  for (int i = 0; i < 4; ++i) {
    int row = rbase + rg * 4 + i;
    float bias = bih[row] + bhh[row];
    float4 o;
    o.x = acc[i][0] + bias; o.y = acc[i][1] + bias;
    o.z = acc[i][2] + bias; o.w = acc[i][3] + bias;
    *(float4*)&PG[((size_t)t * R4H + row) * BB + cg * 4] = o;
  }
}

// ---------------------------------------------------------------------------
__device__ __forceinline__ uint32_t bf16r(float f) {
  uint32_t u = __float_as_uint(f);
  u += 0x7fffu + ((u >> 16) & 1u);
  return u >> 16;
}

// init: hbT[0][b][uh] = pack(bf16(h[2uh]), bf16(h[2uh+1]))  (layout [64][256])
__global__ void init_h(const float* __restrict__ mem, uint32_t* __restrict__ hb)
{
  int idx = blockIdx.x * 256 + threadIdx.x;
  if (idx < HB_STRIDE) {
    int b = idx >> 8, uh = idx & 255;
    float lo = mem[(size_t)b * 1280 + 256 + 2 * uh];
    float hi = mem[(size_t)b * 1280 + 256 + 2 * uh + 1];
    hb[idx] = bf16r(lo) | (bf16r(hi) << 16);
  }
}

// ---------------------------------------------------------------------------
// Cross-XCD h hand-off (proven R6): relaxed agent-scope EXCHANGE stores (RMW
// performed at the IF coherence point; vmcnt(0) ack => globally visible) +
// relaxed agent-scope loads (bypass stale L1/L2). No wbl2/inv sweeps.
// ---------------------------------------------------------------------------
__device__ __forceinline__ void store_coh_u32(uint32_t* p, uint32_t v) {
  (void)__hip_atomic_exchange(p, v, __ATOMIC_RELAXED, __HIP_MEMORY_SCOPE_AGENT);
}
__device__ __forceinline__ uint32_t load_coh_u32(const uint32_t* p) {
  return __hip_atomic_load(p, __ATOMIC_RELAXED, __HIP_MEMORY_SCOPE_AGENT);
}

// gsum addressing: 2-way-max bank pattern via XOR of bit4 with (row>>2)&1
#define GIDX(row, col) (((row) << 6) + ((col) ^ ((((row) >> 2) & 1) << 4)))

// ---------------------------------------------------------------------------
// Persistent LSTM, MFMA edition (R12/R13). grid = 32 WGs x 512 threads.
// WG g owns units [g*16, g*16+16), ALL 64 batches. Per step:
//   gates[64 rows][64 b] = sum_k W_bf16 x h_bf16 via mfma_f32_16x16x32_bf16.
// Wave wu: batch-tile bt=wu>>1, row-tile pair rtp=wu&1 (rt = 2rtp, 2rtp+1).
// W (bf16) preloaded in VGPRs once (128 VGPR) -> zero per-step W traffic.
// h stored TRANSPOSED hbT[b][u/2] so a B-frag = 4 consecutive u32 per lane.
// R13 fix: __launch_bounds__(512) with NO min-waves arg. R12's (512,2)
// clamped to 128 VGPRs, spilling the whole W array to scratch every step
// (VGPR_Count=128, WRITE_SIZE 103->331 MB, 17.8 us/step latency-serialized).
// An 8-wave WG runs alone on its CU -> 2 waves/SIMD -> 256 VGPRs available.
// Sync: single 32-arrival monotonic counter, relaxed agent RMWs (proven).
// ---------------------------------------------------------------------------
__global__ __launch_bounds__(512) void lstm_persistent(
    const float* __restrict__ mem,   // [B][1280]
    const float* __restrict__ Whh,   // [4H][H] f32
    float* __restrict__ PG,          // [T][4H][B]
    uint32_t* __restrict__ hb,       // [2][64][256] packed bf16x2, transposed
    float* __restrict__ outmem,      // [B][1280]
    unsigned* __restrict__ bar)      // cnt@0, gen@64
{
  __shared__ float gsum[64 * 64];    // 16 KB

  const int g    = blockIdx.x;       // 0..31
  const int tid  = threadIdx.x;
  const int wu   = tid >> 6;         // wave 0..7
  const int lane = tid & 63;
  const int l15  = lane & 15;
  const int lq   = lane >> 4;        // 0..3
  const int bt   = wu >> 1;          // batch tile 0..3
  const int rtp  = wu & 1;           // row-tile pair 0..1
  const int u0   = g * 16;

  unsigned* cnt = bar;
  unsigned* gen = bar + 64;

  // ---- A preload: W slice -> bf16 VGPR fragments (once) ----
  short8v aF0[16], aF1[16];
  {
    const float* w0p = Whh + (size_t)((rtp * 2 + 0) * HS + u0 + l15) * HS + lq * 8;
    const float* w1p = Whh + (size_t)((rtp * 2 + 1) * HS + u0 + l15) * HS + lq * 8;
    #pragma unroll
    for (int ks = 0; ks < 16; ++ks) {
      float4 x0 = *(const float4*)(w0p + ks * 32);
      float4 x1 = *(const float4*)(w0p + ks * 32 + 4);
      union { uint32_t u[4]; short8v v; } cv;
      cv.u[0] = bf16r(x0.x) | (bf16r(x0.y) << 16);
      cv.u[1] = bf16r(x0.z) | (bf16r(x0.w) << 16);
      cv.u[2] = bf16r(x1.x) | (bf16r(x1.y) << 16);
      cv.u[3] = bf16r(x1.z) | (bf16r(x1.w) << 16);
      aF0[ks] = cv.v;
      float4 y0 = *(const float4*)(w1p + ks * 32);
      float4 y1 = *(const float4*)(w1p + ks * 32 + 4);
      union { uint32_t u[4]; short8v v; } cw;
      cw.u[0] = bf16r(y0.x) | (bf16r(y0.y) << 16);
      cw.u[1] = bf16r(y0.z) | (bf16r(y0.w) << 16);
      cw.u[2] = bf16r(y1.x) | (bf16r(y1.y) << 16);
      cw.u[3] = bf16r(y1.z) | (bf16r(y1.w) << 16);
      aF1[ks] = cw.v;
    }
  }

  // ---- elementwise state: thread = (unit-pair p = wu, batch eb = lane) ----
  const int p = wu, eb = lane;
  float c0 = mem[(size_t)eb * 1280 + 768 + u0 + 2 * p];
  float c1 = mem[(size_t)eb * 1280 + 768 + u0 + 2 * p + 1];
  float m0 = 0.f, m1 = 0.f, h0l = 0.f, h1l = 0.f;
  if (u0 < HHALF) {
    m0 = mem[(size_t)eb * 1280 + u0 + 2 * p];
    m1 = mem[(size_t)eb * 1280 + u0 + 2 * p + 1];
  }

  // ---- pg prefetch for t=0 (2 tiles x 4 regs per lane) ----
  float pgA[4], pgB[4];
  #pragma unroll
  for (int r = 0; r < 4; ++r) {
    pgA[r] = PG[((size_t)0 * R4H + (rtp * 2 + 0) * HS + u0 + lq * 4 + r) * BB + bt * 16 + l15];
    pgB[r] = PG[((size_t)0 * R4H + (rtp * 2 + 1) * HS + u0 + lq * 4 + r) * BB + bt * 16 + l15];
  }

  for (int t = 0; t < TT; ++t) {
    // ---- B-frag loads (coherent) + MFMA over K=512 ----
    f32x4 acc0 = {0.f, 0.f, 0.f, 0.f}, acc1 = {0.f, 0.f, 0.f, 0.f};
    const uint32_t* hT = hb + (size_t)(t & 1) * HB_STRIDE
                            + (size_t)(bt * 16 + l15) * 256 + lq * 4;
    #pragma unroll
    for (int ks = 0; ks < 16; ++ks) {
      union { uint32_t u[4]; short8v v; } bf;
      #pragma unroll
      for (int m = 0; m < 4; ++m) bf.u[m] = load_coh_u32(hT + ks * 16 + m);
      acc0 = __builtin_amdgcn_mfma_f32_16x16x32_bf16(aF0[ks], bf.v, acc0, 0, 0, 0);
      acc1 = __builtin_amdgcn_mfma_f32_16x16x32_bf16(aF1[ks], bf.v, acc1, 0, 0, 0);
    }

    // ---- add pre-gates, write to gsum (2-way-max banks) ----
    {
      const int colw = bt * 16 + l15;
      #pragma unroll
      for (int r = 0; r < 4; ++r) {
        int row0 = (rtp * 2 + 0) * 16 + lq * 4 + r;
        int row1 = (rtp * 2 + 1) * 16 + lq * 4 + r;
        gsum[GIDX(row0, colw)] = acc0[r] + pgA[r];
        gsum[GIDX(row1, colw)] = acc1[r] + pgB[r];
      }
    }
    __syncthreads();

    // ---- elementwise: 2 cells (units u0+2p, u0+2p+1) x batch eb ----
    {
      const int ul0 = 2 * p, ul1 = 2 * p + 1;
      float gi0 = gsum[GIDX( 0 + ul0, eb)];
      float gf0 = gsum[GIDX(16 + ul0, eb)];
      float gg0 = gsum[GIDX(32 + ul0, eb)];
      float go0 = gsum[GIDX(48 + ul0, eb)];
      float gi1 = gsum[GIDX( 0 + ul1, eb)];
      float gf1 = gsum[GIDX(16 + ul1, eb)];
      float gg1 = gsum[GIDX(32 + ul1, eb)];
      float go1 = gsum[GIDX(48 + ul1, eb)];
      float si0 = 1.f / (1.f + __expf(-gi0));
      float sf0 = 1.f / (1.f + __expf(-gf0));
      float so0 = 1.f / (1.f + __expf(-go0));
      float si1 = 1.f / (1.f + __expf(-gi1));
      float sf1 = 1.f / (1.f + __expf(-gf1));
      float so1 = 1.f / (1.f + __expf(-go1));
      c0 = sf0 * c0 + si0 * tanhf(gg0);
      c1 = sf1 * c1 + si1 * tanhf(gg1);
      float h0 = so0 * tanhf(c0);
      float h1 = so1 * tanhf(c1);
      h0l = h0; h1l = h1;
      // transposed packed store: hbT[eb][g*8+p] (unit pair is thread-local)
      store_coh_u32(&hb[(size_t)((t + 1) & 1) * HB_STRIDE + (size_t)eb * 256 + g * 8 + p],
                    bf16r(h0) | (bf16r(h1) << 16));
      float out0 = h0, out1 = h1;
      if (u0 < HHALF) { m0 = fmaxf(m0, h0); m1 = fmaxf(m1, h1); out0 = m0; out1 = m1; }
      PG[((size_t)t * R4H + u0 + 2 * p) * BB + eb]     = out0;  // stash
      PG[((size_t)t * R4H + u0 + 2 * p + 1) * BB + eb] = out1;
    }

    // ---- barrier: release = vmcnt(0) on the exchange h-stores ----
    asm volatile("s_waitcnt vmcnt(0)" ::: "memory");
    __syncthreads();
    // pg prefetch for t+1 hides under the barrier
    if (t + 1 < TT) {
      #pragma unroll
      for (int r = 0; r < 4; ++r) {
        pgA[r] = PG[((size_t)(t + 1) * R4H + (rtp * 2 + 0) * HS + u0 + lq * 4 + r) * BB + bt * 16 + l15];
        pgB[r] = PG[((size_t)(t + 1) * R4H + (rtp * 2 + 1) * HS + u0 + lq * 4 + r) * BB + bt * 16 + l15];
      }
    }
    if (tid == 0) {
      unsigned a = __hip_atomic_fetch_add(cnt, 1u, __ATOMIC_RELAXED,
                                          __HIP_MEMORY_SCOPE_AGENT);
      if (a == 32u * (unsigned)(t + 1) - 1u)
        (void)__hip_atomic_exchange(gen, (unsigned)(t + 1), __ATOMIC_RELAXED,
                                    __HIP_MEMORY_SCOPE_AGENT);
      // failsafe cap: fast wrong-answer instead of a hang; expected wait ~us.
      int spins = 0;
      while (__hip_atomic_load(gen, __ATOMIC_RELAXED,
                               __HIP_MEMORY_SCOPE_AGENT) < (unsigned)(t + 1)) {
        __builtin_amdgcn_s_sleep(1);
        if (++spins > (1 << 16)) break;
      }
    }
    __syncthreads();
  }

  // ---- finals ----
  outmem[(size_t)eb * 1280 + 256 + u0 + 2 * p]     = h0l;
  outmem[(size_t)eb * 1280 + 256 + u0 + 2 * p + 1] = h1l;
  outmem[(size_t)eb * 1280 + 768 + u0 + 2 * p]     = c0;
  outmem[(size_t)eb * 1280 + 768 + u0 + 2 * p + 1] = c1;
  if (u0 < HHALF) {
    outmem[(size_t)eb * 1280 + u0 + 2 * p]     = m0;
    outmem[(size_t)eb * 1280 + u0 + 2 * p + 1] = m1;
  }
}

// ---------------------------------------------------------------------------
// Phase 3: out[b][t][u] = PG[t][u][b]  (u < 512)
// ---------------------------------------------------------------------------
__global__ __launch_bounds__(256) void transpose_out(
    const float* __restrict__ PG, float* __restrict__ out)
{
  __shared__ __align__(16) float tileS[64][68];
  const int t = blockIdx.x;
  const int u0 = blockIdx.y * 64;
  const int tid = threadIdx.x;

  {
    int cg = tid & 15, rg = tid >> 4;
    const float* src = PG + (size_t)t * R4H * BB + (size_t)u0 * BB;
    #pragma unroll
    for (int i = 0; i < 4; ++i) {
      int u = rg * 4 + i;
      float4 v = *(const float4*)(src + (size_t)u * BB + cg * 4);
      *(float4*)&tileS[u][cg * 4] = v;
    }
  }
  __syncthreads();
  {
    int ug = tid & 15, bg = tid >> 4;
    #pragma unroll
    for (int i = 0; i < 4; ++i) {
      int b = bg * 4 + i;
      float4 o;
      o.x = tileS[ug * 4 + 0][b];
      o.y = tileS[ug * 4 + 1][b];
      o.z = tileS[ug * 4 + 2][b];
      o.w = tileS[ug * 4 + 3][b];
      *(float4*)&out[((size_t)b * TT + t) * HS + u0 + ug * 4] = o;
    }
  }
}

// ---------------------------------------------------------------------------
extern "C" void kernel_launch(void* const* d_in, const int* in_sizes, int n_in,
                              void* d_out, int out_size, void* d_ws, size_t ws_size,
                              hipStream_t stream)
{
  const float* X   = (const float*)d_in[0];
  const float* mem = (const float*)d_in[1];
  const float* Wih = (const float*)d_in[2];
  const float* Whh = (const float*)d_in[3];
  const float* bih = (const float*)d_in[4];
  const float* bhh = (const float*)d_in[5];

  float* out = (float*)d_out;
  float* outmem = out + (size_t)BB * TT * HS;

  float* PG     = (float*)d_ws;                      // 512*2048*64 f32 = 256 MB
  uint32_t* hbp = (uint32_t*)(PG + (size_t)TT * R4H * BB);  // 2*16384 u32
  unsigned* bar = (unsigned*)(hbp + 2 * HB_STRIDE);  // 2048 u32

  hipMemsetAsync(bar, 0, 2048 * sizeof(unsigned), stream);
  init_h<<<dim3(HB_STRIDE / 256), dim3(256), 0, stream>>>(mem, hbp);
  pregemm<<<dim3(TT, 32), dim3(256), 0, stream>>>(X, Wih, bih, bhh, PG);
  lstm_persistent<<<dim3(32), dim3(512), 0, stream>>>(mem, Whh, PG, hbp, outmem, bar);
  transpose_out<<<dim3(TT, 8), dim3(256), 0, stream>>>(PG, out);
}

// Round 14
// 9501.604 us; speedup vs baseline: 1.0004x; 1.0000x over previous
//
#include <hip/hip_runtime.h>
#include <stdint.h>

#define TT 512
#define BB 64
#define II 256
#define HS 512          // H
#define HHALF 256       // HH
#define R4H 2048        // 4*H
#define HB_STRIDE 16384 // 64 batches * 256 unit-pair words per h buffer

typedef __attribute__((ext_vector_type(8))) short short8v;  // 8 bf16 = 4 VGPR
typedef __attribute__((ext_vector_type(4))) float f32x4;

// ---------------------------------------------------------------------------
// Phase 1: PG[t][r][b] = (b_ih[r]+b_hh[r]) + sum_k W_ih[r][k] * X[b][t][k]
// ---------------------------------------------------------------------------
__global__ __launch_bounds__(256) void pregemm(
    const float* __restrict__ X,    // [B][T][I]
    const float* __restrict__ Wih,  // [4H][I]
    const float* __restrict__ bih,
    const float* __restrict__ bhh,
    float* __restrict__ PG)         // [T][4H][B]
{
  __shared__ __align__(16) float Xs[64][68];
  __shared__ __align__(16) float Ws[64][68];
  const int t = blockIdx.x;
  const int rbase = blockIdx.y * 64;
  const int tid = threadIdx.x;
  const int cg = tid & 15;
  const int rg = tid >> 4;

  float acc[4][4] = {};

  for (int k0 = 0; k0 < II; k0 += 64) {
    {
      int b = tid >> 2, kq = tid & 3;
      const float* src = X + ((size_t)b * TT + t) * II + k0 + kq * 16;
      #pragma unroll
      for (int i = 0; i < 16; i += 4) {
        float4 v = *(const float4*)(src + i);
        int kk = kq * 16 + i;
        Xs[kk + 0][b] = v.x; Xs[kk + 1][b] = v.y;
        Xs[kk + 2][b] = v.z; Xs[kk + 3][b] = v.w;
      }
    }
    {
      int r = tid >> 2, kq = tid & 3;
      const float* src = Wih + (size_t)(rbase + r) * II + k0 + kq * 16;
      #pragma unroll
      for (int i = 0; i < 16; i += 4) {
        float4 v = *(const float4*)(src + i);
        int kk = kq * 16 + i;
        Ws[kk + 0][r] = v.x; Ws[kk + 1][r] = v.y;
        Ws[kk + 2][r] = v.z; Ws[kk + 3][r] = v.w;
      }
    }
    __syncthreads();
    #pragma unroll 8
    for (int kk = 0; kk < 64; ++kk) {
      float4 a = *(const float4*)&Ws[kk][rg * 4];
      float4 x = *(const float4*)&Xs[kk][cg * 4];
      float av[4] = {a.x, a.y, a.z, a.w};
      float xv[4] = {x.x, x.y, x.z, x.w};
      #pragma unroll
      for (int i = 0; i < 4; ++i)
        #pragma unroll
        for (int j = 0; j < 4; ++j)
          acc[i][j] = fmaf(av[i], xv[j], acc[i][j]);
    }
    __syncthreads();
  }

  #pragma unroll
  for (int i = 0; i < 4; ++i) {
    int row = rbase + rg * 4 + i;
    float bias = bih[row] + bhh[row];
    float4 o;
    o.x = acc[i][0] + bias; o.y = acc[i][1] + bias;
    o.z = acc[i][2] + bias; o.w = acc[i][3] + bias;
    *(float4*)&PG[((size_t)t * R4H + row) * BB + cg * 4] = o;
  }
}

// ---------------------------------------------------------------------------
__device__ __forceinline__ uint32_t bf16r(float f) {
  uint32_t u = __float_as_uint(f);
  u += 0x7fffu + ((u >> 16) & 1u);
  return u >> 16;
}

// init: hbT[0][b][uh] = pack(bf16(h[2uh]), bf16(h[2uh+1]))  (layout [64][256])
__global__ void init_h(const float* __restrict__ mem, uint32_t* __restrict__ hb)
{
  int idx = blockIdx.x * 256 + threadIdx.x;
  if (idx < HB_STRIDE) {
    int b = idx >> 8, uh = idx & 255;
    float lo = mem[(size_t)b * 1280 + 256 + 2 * uh];
    float hi = mem[(size_t)b * 1280 + 256 + 2 * uh + 1];
    hb[idx] = bf16r(lo) | (bf16r(hi) << 16);
  }
}

// ---------------------------------------------------------------------------
// Cross-XCD h hand-off (proven R6): relaxed agent-scope EXCHANGE stores (RMW
// performed at the IF coherence point; vmcnt(0) ack => globally visible) +
// relaxed agent-scope loads (bypass stale L1/L2). No wbl2/inv sweeps.
// ---------------------------------------------------------------------------
__device__ __forceinline__ void store_coh_u32(uint32_t* p, uint32_t v) {
  (void)__hip_atomic_exchange(p, v, __ATOMIC_RELAXED, __HIP_MEMORY_SCOPE_AGENT);
}
__device__ __forceinline__ uint32_t load_coh_u32(const uint32_t* p) {
  return __hip_atomic_load(p, __ATOMIC_RELAXED, __HIP_MEMORY_SCOPE_AGENT);
}

// gsum addressing: 2-way-max bank pattern via XOR of bit4 with (row>>2)&1
#define GIDX(row, col) (((row) << 6) + ((col) ^ ((((row) >> 2) & 1) << 4)))

// ---------------------------------------------------------------------------
// Persistent LSTM, MFMA edition. grid = 32 WGs x 512 threads.
// WG g owns units [g*16, g*16+16), ALL 64 batches. Per step:
//   gates[64 rows][64 b] = sum_k W_bf16 x h_bf16 via mfma_f32_16x16x32_bf16.
// Wave wu: batch-tile bt=wu>>1, row-tile pair rtp=wu&1 (rt = 2rtp, 2rtp+1).
// W (bf16) preloaded in VGPRs once (128 VGPR) -> zero per-step W traffic.
// h stored TRANSPOSED hbT[b][u/2] so a B-frag = 4 consecutive u32 per lane.
//
// R14 occupancy fix: amdgpu_waves_per_eu(2,2). The backend's DEFAULT target
// is 4 waves/EU; VGPR pool = 512/SIMD (m69) => cap 512/4 = 128, which
// spilled the whole 128-VGPR W array to scratch every step (R12/R13:
// VGPR_Count=128, WRITE_SIZE 103->331 MB, ~17.8 us/step). launch_bounds
// could not express "exactly 2 waves/EU"; the clang attribute can:
// min=2 waves/EU => 256 VGPRs/lane, and an 8-wave WG at 2/SIMD launches.
// Live set ~234 VGPRs -> zero spill.
// Sync: single 32-arrival monotonic counter, relaxed agent RMWs (proven).
// ---------------------------------------------------------------------------
__global__
__attribute__((amdgpu_flat_work_group_size(512, 512), amdgpu_waves_per_eu(2, 2)))
void lstm_persistent(
    const float* __restrict__ mem,   // [B][1280]
    const float* __restrict__ Whh,   // [4H][H] f32
    float* __restrict__ PG,          // [T][4H][B]
    uint32_t* __restrict__ hb,       // [2][64][256] packed bf16x2, transposed
    float* __restrict__ outmem,      // [B][1280]
    unsigned* __restrict__ bar)      // cnt@0, gen@64
{
  __shared__ float gsum[64 * 64];    // 16 KB

  const int g    = blockIdx.x;       // 0..31
  const int tid  = threadIdx.x;
  const int wu   = tid >> 6;         // wave 0..7
  const int lane = tid & 63;
  const int l15  = lane & 15;
  const int lq   = lane >> 4;        // 0..3
  const int bt   = wu >> 1;          // batch tile 0..3
  const int rtp  = wu & 1;           // row-tile pair 0..1
  const int u0   = g * 16;

  unsigned* cnt = bar;
  unsigned* gen = bar + 64;

  // ---- A preload: W slice -> bf16 VGPR fragments (once) ----
  short8v aF0[16], aF1[16];
  {
    const float* w0p = Whh + (size_t)((rtp * 2 + 0) * HS + u0 + l15) * HS + lq * 8;
    const float* w1p = Whh + (size_t)((rtp * 2 + 1) * HS + u0 + l15) * HS + lq * 8;
    #pragma unroll
    for (int ks = 0; ks < 16; ++ks) {
      float4 x0 = *(const float4*)(w0p + ks * 32);
      float4 x1 = *(const float4*)(w0p + ks * 32 + 4);
      union { uint32_t u[4]; short8v v; } cv;
      cv.u[0] = bf16r(x0.x) | (bf16r(x0.y) << 16);
      cv.u[1] = bf16r(x0.z) | (bf16r(x0.w) << 16);
      cv.u[2] = bf16r(x1.x) | (bf16r(x1.y) << 16);
      cv.u[3] = bf16r(x1.z) | (bf16r(x1.w) << 16);
      aF0[ks] = cv.v;
      float4 y0 = *(const float4*)(w1p + ks * 32);
      float4 y1 = *(const float4*)(w1p + ks * 32 + 4);
      union { uint32_t u[4]; short8v v; } cw;
      cw.u[0] = bf16r(y0.x) | (bf16r(y0.y) << 16);
      cw.u[1] = bf16r(y0.z) | (bf16r(y0.w) << 16);
      cw.u[2] = bf16r(y1.x) | (bf16r(y1.y) << 16);
      cw.u[3] = bf16r(y1.z) | (bf16r(y1.w) << 16);
      aF1[ks] = cw.v;
    }
  }

  // ---- elementwise state: thread = (unit-pair p = wu, batch eb = lane) ----
  const int p = wu, eb = lane;
  float c0 = mem[(size_t)eb * 1280 + 768 + u0 + 2 * p];
  float c1 = mem[(size_t)eb * 1280 + 768 + u0 + 2 * p + 1];
  float m0 = 0.f, m1 = 0.f, h0l = 0.f, h1l = 0.f;
  if (u0 < HHALF) {
    m0 = mem[(size_t)eb * 1280 + u0 + 2 * p];
    m1 = mem[(size_t)eb * 1280 + u0 + 2 * p + 1];
  }

  // ---- pg prefetch for t=0 (2 tiles x 4 regs per lane) ----
  float pgA[4], pgB[4];
  #pragma unroll
  for (int r = 0; r < 4; ++r) {
    pgA[r] = PG[((size_t)0 * R4H + (rtp * 2 + 0) * HS + u0 + lq * 4 + r) * BB + bt * 16 + l15];
    pgB[r] = PG[((size_t)0 * R4H + (rtp * 2 + 1) * HS + u0 + lq * 4 + r) * BB + bt * 16 + l15];
  }

  for (int t = 0; t < TT; ++t) {
    // ---- B-frag loads (coherent) + MFMA over K=512 ----
    f32x4 acc0 = {0.f, 0.f, 0.f, 0.f}, acc1 = {0.f, 0.f, 0.f, 0.f};
    const uint32_t* hT = hb + (size_t)(t & 1) * HB_STRIDE
                            + (size_t)(bt * 16 + l15) * 256 + lq * 4;
    #pragma unroll
    for (int ks = 0; ks < 16; ++ks) {
      union { uint32_t u[4]; short8v v; } bf;
      #pragma unroll
      for (int m = 0; m < 4; ++m) bf.u[m] = load_coh_u32(hT + ks * 16 + m);
      acc0 = __builtin_amdgcn_mfma_f32_16x16x32_bf16(aF0[ks], bf.v, acc0, 0, 0, 0);
      acc1 = __builtin_amdgcn_mfma_f32_16x16x32_bf16(aF1[ks], bf.v, acc1, 0, 0, 0);
    }

    // ---- add pre-gates, write to gsum (2-way-max banks) ----
    {
      const int colw = bt * 16 + l15;
      #pragma unroll
      for (int r = 0; r < 4; ++r) {
        int row0 = (rtp * 2 + 0) * 16 + lq * 4 + r;
        int row1 = (rtp * 2 + 1) * 16 + lq * 4 + r;
        gsum[GIDX(row0, colw)] = acc0[r] + pgA[r];
        gsum[GIDX(row1, colw)] = acc1[r] + pgB[r];
      }
    }
    __syncthreads();

    // ---- elementwise: 2 cells (units u0+2p, u0+2p+1) x batch eb ----
    {
      const int ul0 = 2 * p, ul1 = 2 * p + 1;
      float gi0 = gsum[GIDX( 0 + ul0, eb)];
      float gf0 = gsum[GIDX(16 + ul0, eb)];
      float gg0 = gsum[GIDX(32 + ul0, eb)];
      float go0 = gsum[GIDX(48 + ul0, eb)];
      float gi1 = gsum[GIDX( 0 + ul1, eb)];
      float gf1 = gsum[GIDX(16 + ul1, eb)];
      float gg1 = gsum[GIDX(32 + ul1, eb)];
      float go1 = gsum[GIDX(48 + ul1, eb)];
      float si0 = 1.f / (1.f + __expf(-gi0));
      float sf0 = 1.f / (1.f + __expf(-gf0));
      float so0 = 1.f / (1.f + __expf(-go0));
      float si1 = 1.f / (1.f + __expf(-gi1));
      float sf1 = 1.f / (1.f + __expf(-gf1));
      float so1 = 1.f / (1.f + __expf(-go1));
      c0 = sf0 * c0 + si0 * tanhf(gg0);
      c1 = sf1 * c1 + si1 * tanhf(gg1);
      float h0 = so0 * tanhf(c0);
      float h1 = so1 * tanhf(c1);
      h0l = h0; h1l = h1;
      // transposed packed store: hbT[eb][g*8+p] (unit pair is thread-local)
      store_coh_u32(&hb[(size_t)((t + 1) & 1) * HB_STRIDE + (size_t)eb * 256 + g * 8 + p],
                    bf16r(h0) | (bf16r(h1) << 16));
      float out0 = h0, out1 = h1;
      if (u0 < HHALF) { m0 = fmaxf(m0, h0); m1 = fmaxf(m1, h1); out0 = m0; out1 = m1; }
      PG[((size_t)t * R4H + u0 + 2 * p) * BB + eb]     = out0;  // stash
      PG[((size_t)t * R4H + u0 + 2 * p + 1) * BB + eb] = out1;
    }

    // ---- barrier: release = vmcnt(0) on the exchange h-stores ----
    asm volatile("s_waitcnt vmcnt(0)" ::: "memory");
    __syncthreads();
    // pg prefetch for t+1 hides under the barrier
    if (t + 1 < TT) {
      #pragma unroll
      for (int r = 0; r < 4; ++r) {
        pgA[r] = PG[((size_t)(t + 1) * R4H + (rtp * 2 + 0) * HS + u0 + lq * 4 + r) * BB + bt * 16 + l15];
        pgB[r] = PG[((size_t)(t + 1) * R4H + (rtp * 2 + 1) * HS + u0 + lq * 4 + r) * BB + bt * 16 + l15];
      }
    }
    if (tid == 0) {
      unsigned a = __hip_atomic_fetch_add(cnt, 1u, __ATOMIC_RELAXED,
                                          __HIP_MEMORY_SCOPE_AGENT);
      if (a == 32u * (unsigned)(t + 1) - 1u)
        (void)__hip_atomic_exchange(gen, (unsigned)(t + 1), __ATOMIC_RELAXED,
                                    __HIP_MEMORY_SCOPE_AGENT);
      // failsafe cap: fast wrong-answer instead of a hang; expected wait ~us.
      int spins = 0;
      while (__hip_atomic_load(gen, __ATOMIC_RELAXED,
                               __HIP_MEMORY_SCOPE_AGENT) < (unsigned)(t + 1)) {
        __builtin_amdgcn_s_sleep(1);
        if (++spins > (1 << 16)) break;
      }
    }
    __syncthreads();
  }

  // ---- finals ----
  outmem[(size_t)eb * 1280 + 256 + u0 + 2 * p]     = h0l;
  outmem[(size_t)eb * 1280 + 256 + u0 + 2 * p + 1] = h1l;
  outmem[(size_t)eb * 1280 + 768 + u0 + 2 * p]     = c0;
  outmem[(size_t)eb * 1280 + 768 + u0 + 2 * p + 1] = c1;
  if (u0 < HHALF) {
    outmem[(size_t)eb * 1280 + u0 + 2 * p]     = m0;
    outmem[(size_t)eb * 1280 + u0 + 2 * p + 1] = m1;
  }
}

// ---------------------------------------------------------------------------
// Phase 3: out[b][t][u] = PG[t][u][b]  (u < 512)
// ---------------------------------------------------------------------------
__global__ __launch_bounds__(256) void transpose_out(
    const float* __restrict__ PG, float* __restrict__ out)
{
  __shared__ __align__(16) float tileS[64][68];
  const int t = blockIdx.x;
  const int u0 = blockIdx.y * 64;
  const int tid = threadIdx.x;

  {
    int cg = tid & 15, rg = tid >> 4;
    const float* src = PG + (size_t)t * R4H * BB + (size_t)u0 * BB;
    #pragma unroll
    for (int i = 0; i < 4; ++i) {
      int u = rg * 4 + i;
      float4 v = *(const float4*)(src + (size_t)u * BB + cg * 4);
      *(float4*)&tileS[u][cg * 4] = v;
    }
  }
  __syncthreads();
  {
    int ug = tid & 15, bg = tid >> 4;
    #pragma unroll
    for (int i = 0; i < 4; ++i) {
      int b = bg * 4 + i;
      float4 o;
      o.x = tileS[ug * 4 + 0][b];
      o.y = tileS[ug * 4 + 1][b];
      o.z = tileS[ug * 4 + 2][b];
      o.w = tileS[ug * 4 + 3][b];
      *(float4*)&out[((size_t)b * TT + t) * HS + u0 + ug * 4] = o;
    }
  }
}

// ---------------------------------------------------------------------------
extern "C" void kernel_launch(void* const* d_in, const int* in_sizes, int n_in,
                              void* d_out, int out_size, void* d_ws, size_t ws_size,
                              hipStream_t stream)
{
  const float* X   = (const float*)d_in[0];
  const float* mem = (const float*)d_in[1];
  const float* Wih = (const float*)d_in[2];
  const float* Whh = (const float*)d_in[3];
  const float* bih = (const float*)d_in[4];
  const float* bhh = (const float*)d_in[5];

  float* out = (float*)d_out;
  float* outmem = out + (size_t)BB * TT * HS;

  float* PG     = (float*)d_ws;                      // 512*2048*64 f32 = 256 MB
  uint32_t* hbp = (uint32_t*)(PG + (size_t)TT * R4H * BB);  // 2*16384 u32
  unsigned* bar = (unsigned*)(hbp + 2 * HB_STRIDE);  // 2048 u32

  hipMemsetAsync(bar, 0, 2048 * sizeof(unsigned), stream);
  init_h<<<dim3(HB_STRIDE / 256), dim3(256), 0, stream>>>(mem, hbp);
  pregemm<<<dim3(TT, 32), dim3(256), 0, stream>>>(X, Wih, bih, bhh, PG);
  lstm_persistent<<<dim3(32), dim3(512), 0, stream>>>(mem, Whh, PG, hbp, outmem, bar);
  transpose_out<<<dim3(TT, 8), dim3(256), 0, stream>>>(PG, out);
}

// Round 16
// 9236.651 us; speedup vs baseline: 1.0291x; 1.0287x over previous
//
#include <hip/hip_runtime.h>
#include <stdint.h>

#define TT 512
#define BB 64
#define II 256
#define HS 512          // H
#define HHALF 256       // HH
#define R4H 2048        // 4*H
#define HB_STRIDE 16384 // 64 batches * 256 unit-pair words per h buffer

typedef __attribute__((ext_vector_type(8))) short short8v;  // 8 bf16 = 4 VGPR
typedef __attribute__((ext_vector_type(4))) float f32x4;

// ---------------------------------------------------------------------------
// Phase 1: PG[t][r][b] = (b_ih[r]+b_hh[r]) + sum_k W_ih[r][k] * X[b][t][k]
// ---------------------------------------------------------------------------
__global__ __launch_bounds__(256) void pregemm(
    const float* __restrict__ X,    // [B][T][I]
    const float* __restrict__ Wih,  // [4H][I]
    const float* __restrict__ bih,
    const float* __restrict__ bhh,
    float* __restrict__ PG)         // [T][4H][B]
{
  __shared__ __align__(16) float Xs[64][68];
  __shared__ __align__(16) float Ws[64][68];
  const int t = blockIdx.x;
  const int rbase = blockIdx.y * 64;
  const int tid = threadIdx.x;
  const int cg = tid & 15;
  const int rg = tid >> 4;

  float acc[4][4] = {};

  for (int k0 = 0; k0 < II; k0 += 64) {
    {
      int b = tid >> 2, kq = tid & 3;
      const float* src = X + ((size_t)b * TT + t) * II + k0 + kq * 16;
      #pragma unroll
      for (int i = 0; i < 16; i += 4) {
        float4 v = *(const float4*)(src + i);
        int kk = kq * 16 + i;
        Xs[kk + 0][b] = v.x; Xs[kk + 1][b] = v.y;
        Xs[kk + 2][b] = v.z; Xs[kk + 3][b] = v.w;
      }
    }
    {
      int r = tid >> 2, kq = tid & 3;
      const float* src = Wih + (size_t)(rbase + r) * II + k0 + kq * 16;
      #pragma unroll
      for (int i = 0; i < 16; i += 4) {
        float4 v = *(const float4*)(src + i);
        int kk = kq * 16 + i;
        Ws[kk + 0][r] = v.x; Ws[kk + 1][r] = v.y;
        Ws[kk + 2][r] = v.z; Ws[kk + 3][r] = v.w;
      }
    }
    __syncthreads();
    #pragma unroll 8
    for (int kk = 0; kk < 64; ++kk) {
      float4 a = *(const float4*)&Ws[kk][rg * 4];
      float4 x = *(const float4*)&Xs[kk][cg * 4];
      float av[4] = {a.x, a.y, a.z, a.w};
      float xv[4] = {x.x, x.y, x.z, x.w};
      #pragma unroll
      for (int i = 0; i < 4; ++i)
        #pragma unroll
        for (int j = 0; j < 4; ++j)
          acc[i][j] = fmaf(av[i], xv[j], acc[i][j]);
    }
    __syncthreads();
  }

  #pragma unroll
  for (int i = 0; i < 4; ++i) {
    int row = rbase + rg * 4 + i;
    float bias = bih[row] + bhh[row];
    float4 o;
    o.x = acc[i][0] + bias; o.y = acc[i][1] + bias;
    o.z = acc[i][2] + bias; o.w = acc[i][3] + bias;
    *(float4*)&PG[((size_t)t * R4H + row) * BB + cg * 4] = o;
  }
}

// ---------------------------------------------------------------------------
__device__ __forceinline__ uint32_t bf16r(float f) {
  uint32_t u = __float_as_uint(f);
  u += 0x7fffu + ((u >> 16) & 1u);
  return u >> 16;
}

// init: hbT[0][b][uh] = pack(bf16(h[2uh]), bf16(h[2uh+1]))  (layout [64][256])
__global__ void init_h(const float* __restrict__ mem, uint32_t* __restrict__ hb)
{
  int idx = blockIdx.x * 256 + threadIdx.x;
  if (idx < HB_STRIDE) {
    int b = idx >> 8, uh = idx & 255;
    float lo = mem[(size_t)b * 1280 + 256 + 2 * uh];
    float hi = mem[(size_t)b * 1280 + 256 + 2 * uh + 1];
    hb[idx] = bf16r(lo) | (bf16r(hi) << 16);
  }
}

// ---------------------------------------------------------------------------
// Cross-XCD h hand-off (proven R6): relaxed agent-scope EXCHANGE stores (RMW
// performed at the IF coherence point; vmcnt(0) ack => globally visible) +
// relaxed agent-scope loads (bypass stale L1/L2). No wbl2/inv sweeps.
// ---------------------------------------------------------------------------
__device__ __forceinline__ void store_coh_u32(uint32_t* p, uint32_t v) {
  (void)__hip_atomic_exchange(p, v, __ATOMIC_RELAXED, __HIP_MEMORY_SCOPE_AGENT);
}
__device__ __forceinline__ uint32_t load_coh_u32(const uint32_t* p) {
  return __hip_atomic_load(p, __ATOMIC_RELAXED, __HIP_MEMORY_SCOPE_AGENT);
}

// gsum addressing: 2-way-max bank pattern via XOR of bit4 with (row>>2)&1
#define GIDX(row, col) (((row) << 6) + ((col) ^ ((((row) >> 2) & 1) << 4)))

// ---------------------------------------------------------------------------
// Persistent LSTM, MFMA edition (R15). grid = 64 WGs x 512 threads.
// WG g owns units [g*8, g*8+8) = 32 gate rows, ALL 64 batches. Per step:
//   gates[32 rows][64 b] = sum_k W_bf16 x h_bf16 via mfma_f32_16x16x32_bf16.
// Wave wu = ONE C-tile: row-tile rt = wu>>2, batch-tile bt = wu&3.
// Per-lane VGPR live set fits the 128 budget (R12-R14 lesson: the backend
// pins 512-thread kernels at 128 arch VGPRs; neither __launch_bounds__ nor
// amdgpu_waves_per_eu lifted it, so the 2-row-tile/wave design spilled its
// 128-VGPR W array to scratch every step — WRITE_SIZE 331 MB, 17.8 us/step):
//   W aF[16]=64 + B-frag ~8-16 + acc 4 + pg 4 + state 6 + temps ~15 ~= 110.
// Local gate row lr in [0,32): gate q = lr>>3, unit du = lr&7;
// global row = q*HS + g*8 + du. A-frag row = rt*16 + l15.
// h stored TRANSPOSED hbT[b][u/2]; B-frag = 4 consecutive u32 per lane.
// Elementwise: tid<256, thread = (unit-pair p = tid>>6, batch = lane).
// Sync: single 64-arrival monotonic counter, relaxed agent RMWs (proven).
// ---------------------------------------------------------------------------
__global__ __launch_bounds__(512) void lstm_persistent(
    const float* __restrict__ mem,   // [B][1280]
    const float* __restrict__ Whh,   // [4H][H] f32
    float* __restrict__ PG,          // [T][4H][B]
    uint32_t* __restrict__ hb,       // [2][64][256] packed bf16x2, transposed
    float* __restrict__ outmem,      // [B][1280]
    unsigned* __restrict__ bar)      // cnt@0, gen@64
{
  __shared__ float gsum[32 * 64];    // 8 KB

  const int g    = blockIdx.x;       // 0..63
  const int tid  = threadIdx.x;
  const int wu   = tid >> 6;         // wave 0..7
  const int lane = tid & 63;
  const int l15  = lane & 15;
  const int lq   = lane >> 4;        // 0..3
  const int bt   = wu & 3;           // batch tile 0..3
  const int rt   = wu >> 2;          // row tile 0..1
  const int u0   = g * 8;

  unsigned* cnt = bar;
  unsigned* gen = bar + 64;

  // ---- A preload: ONE row-tile of W -> bf16 VGPR fragments (64 VGPRs) ----
  short8v aF[16];
  {
    const int lrA = rt * 16 + l15;                       // local gate row
    const int growA = (lrA >> 3) * HS + u0 + (lrA & 7);  // global gate row
    const float* wp = Whh + (size_t)growA * HS + lq * 8;
    #pragma unroll
    for (int ks = 0; ks < 16; ++ks) {
      float4 x0 = *(const float4*)(wp + ks * 32);
      float4 x1 = *(const float4*)(wp + ks * 32 + 4);
      union { uint32_t u[4]; short8v v; } cv;
      cv.u[0] = bf16r(x0.x) | (bf16r(x0.y) << 16);
      cv.u[1] = bf16r(x0.z) | (bf16r(x0.w) << 16);
      cv.u[2] = bf16r(x1.x) | (bf16r(x1.y) << 16);
      cv.u[3] = bf16r(x1.z) | (bf16r(x1.w) << 16);
      aF[ks] = cv.v;
    }
  }

  // ---- elementwise state: tid<256, thread = (pair p = tid>>6, batch eb) ----
  const int p = tid >> 6;            // unit-pair 0..3 (valid for tid<256)
  const int eb = lane;
  float c0 = 0.f, c1 = 0.f, m0 = 0.f, m1 = 0.f, h0l = 0.f, h1l = 0.f;
  if (tid < 256) {
    c0 = mem[(size_t)eb * 1280 + 768 + u0 + 2 * p];
    c1 = mem[(size_t)eb * 1280 + 768 + u0 + 2 * p + 1];
    if (u0 < HHALF) {
      m0 = mem[(size_t)eb * 1280 + u0 + 2 * p];
      m1 = mem[(size_t)eb * 1280 + u0 + 2 * p + 1];
    }
  }

  // ---- pg prefetch for t=0 (1 tile x 4 regs per lane) ----
  float pg[4];
  #pragma unroll
  for (int r = 0; r < 4; ++r) {
    int lr = rt * 16 + lq * 4 + r;
    pg[r] = PG[((size_t)0 * R4H + (lr >> 3) * HS + u0 + (lr & 7)) * BB + bt * 16 + l15];
  }

  for (int t = 0; t < TT; ++t) {
    // ---- B-frag loads (coherent) + MFMA over K=512 ----
    f32x4 acc = {0.f, 0.f, 0.f, 0.f};
    const uint32_t* hT = hb + (size_t)(t & 1) * HB_STRIDE
                            + (size_t)(bt * 16 + l15) * 256 + lq * 4;
    #pragma unroll
    for (int ks = 0; ks < 16; ++ks) {
      union { uint32_t u[4]; short8v v; } bf;
      #pragma unroll
      for (int m = 0; m < 4; ++m) bf.u[m] = load_coh_u32(hT + ks * 16 + m);
      acc = __builtin_amdgcn_mfma_f32_16x16x32_bf16(aF[ks], bf.v, acc, 0, 0, 0);
    }

    // ---- add pre-gates, write to gsum (2-way-max banks) ----
    {
      const int colw = bt * 16 + l15;
      #pragma unroll
      for (int r = 0; r < 4; ++r) {
        int row = rt * 16 + lq * 4 + r;
        gsum[GIDX(row, colw)] = acc[r] + pg[r];
      }
    }
    __syncthreads();

    // ---- elementwise: 2 cells (units u0+2p, u0+2p+1) x batch eb ----
    if (tid < 256) {
      const int ul0 = 2 * p, ul1 = 2 * p + 1;
      float gi0 = gsum[GIDX( 0 + ul0, eb)];
      float gf0 = gsum[GIDX( 8 + ul0, eb)];
      float gg0 = gsum[GIDX(16 + ul0, eb)];
      float go0 = gsum[GIDX(24 + ul0, eb)];
      float gi1 = gsum[GIDX( 0 + ul1, eb)];
      float gf1 = gsum[GIDX( 8 + ul1, eb)];
      float gg1 = gsum[GIDX(16 + ul1, eb)];
      float go1 = gsum[GIDX(24 + ul1, eb)];
      float si0 = 1.f / (1.f + __expf(-gi0));
      float sf0 = 1.f / (1.f + __expf(-gf0));
      float so0 = 1.f / (1.f + __expf(-go0));
      float si1 = 1.f / (1.f + __expf(-gi1));
      float sf1 = 1.f / (1.f + __expf(-gf1));
      float so1 = 1.f / (1.f + __expf(-go1));
      c0 = sf0 * c0 + si0 * tanhf(gg0);
      c1 = sf1 * c1 + si1 * tanhf(gg1);
      float h0 = so0 * tanhf(c0);
      float h1 = so1 * tanhf(c1);
      h0l = h0; h1l = h1;
      // transposed packed store: hbT[eb][g*4+p] (unit pair is thread-local)
      store_coh_u32(&hb[(size_t)((t + 1) & 1) * HB_STRIDE + (size_t)eb * 256 + g * 4 + p],
                    bf16r(h0) | (bf16r(h1) << 16));
      float out0 = h0, out1 = h1;
      if (u0 < HHALF) { m0 = fmaxf(m0, h0); m1 = fmaxf(m1, h1); out0 = m0; out1 = m1; }
      PG[((size_t)t * R4H + u0 + 2 * p) * BB + eb]     = out0;  // stash
      PG[((size_t)t * R4H + u0 + 2 * p + 1) * BB + eb] = out1;
    }

    // ---- barrier: release = vmcnt(0) on the exchange h-stores ----
    asm volatile("s_waitcnt vmcnt(0)" ::: "memory");
    __syncthreads();
    // pg prefetch for t+1 hides under the barrier
    if (t + 1 < TT) {
      #pragma unroll
      for (int r = 0; r < 4; ++r) {
        int lr = rt * 16 + lq * 4 + r;
        pg[r] = PG[((size_t)(t + 1) * R4H + (lr >> 3) * HS + u0 + (lr & 7)) * BB + bt * 16 + l15];
      }
    }
    if (tid == 0) {
      unsigned a = __hip_atomic_fetch_add(cnt, 1u, __ATOMIC_RELAXED,
                                          __HIP_MEMORY_SCOPE_AGENT);
      if (a == 64u * (unsigned)(t + 1) - 1u)
        (void)__hip_atomic_exchange(gen, (unsigned)(t + 1), __ATOMIC_RELAXED,
                                    __HIP_MEMORY_SCOPE_AGENT);
      // failsafe cap: fast wrong-answer instead of a hang; expected wait ~us.
      int spins = 0;
      while (__hip_atomic_load(gen, __ATOMIC_RELAXED,
                               __HIP_MEMORY_SCOPE_AGENT) < (unsigned)(t + 1)) {
        __builtin_amdgcn_s_sleep(1);
        if (++spins > (1 << 16)) break;
      }
    }
    __syncthreads();
  }

  // ---- finals ----
  if (tid < 256) {
    outmem[(size_t)eb * 1280 + 256 + u0 + 2 * p]     = h0l;
    outmem[(size_t)eb * 1280 + 256 + u0 + 2 * p + 1] = h1l;
    outmem[(size_t)eb * 1280 + 768 + u0 + 2 * p]     = c0;
    outmem[(size_t)eb * 1280 + 768 + u0 + 2 * p + 1] = c1;
    if (u0 < HHALF) {
      outmem[(size_t)eb * 1280 + u0 + 2 * p]     = m0;
      outmem[(size_t)eb * 1280 + u0 + 2 * p + 1] = m1;
    }
  }
}

// ---------------------------------------------------------------------------
// Phase 3: out[b][t][u] = PG[t][u][b]  (u < 512)
// ---------------------------------------------------------------------------
__global__ __launch_bounds__(256) void transpose_out(
    const float* __restrict__ PG, float* __restrict__ out)
{
  __shared__ __align__(16) float tileS[64][68];
  const int t = blockIdx.x;
  const int u0 = blockIdx.y * 64;
  const int tid = threadIdx.x;

  {
    int cg = tid & 15, rg = tid >> 4;
    const float* src = PG + (size_t)t * R4H * BB + (size_t)u0 * BB;
    #pragma unroll
    for (int i = 0; i < 4; ++i) {
      int u = rg * 4 + i;
      float4 v = *(const float4*)(src + (size_t)u * BB + cg * 4);
      *(float4*)&tileS[u][cg * 4] = v;
    }
  }
  __syncthreads();
  {
    int ug = tid & 15, bg = tid >> 4;
    #pragma unroll
    for (int i = 0; i < 4; ++i) {
      int b = bg * 4 + i;
      float4 o;
      o.x = tileS[ug * 4 + 0][b];
      o.y = tileS[ug * 4 + 1][b];
      o.z = tileS[ug * 4 + 2][b];
      o.w = tileS[ug * 4 + 3][b];
      *(float4*)&out[((size_t)b * TT + t) * HS + u0 + ug * 4] = o;
    }
  }
}

// ---------------------------------------------------------------------------
extern "C" void kernel_launch(void* const* d_in, const int* in_sizes, int n_in,
                              void* d_out, int out_size, void* d_ws, size_t ws_size,
                              hipStream_t stream)
{
  const float* X   = (const float*)d_in[0];
  const float* mem = (const float*)d_in[1];
  const float* Wih = (const float*)d_in[2];
  const float* Whh = (const float*)d_in[3];
  const float* bih = (const float*)d_in[4];
  const float* bhh = (const float*)d_in[5];

  float* out = (float*)d_out;
  float* outmem = out + (size_t)BB * TT * HS;

  float* PG     = (float*)d_ws;                      // 512*2048*64 f32 = 256 MB
  uint32_t* hbp = (uint32_t*)(PG + (size_t)TT * R4H * BB);  // 2*16384 u32
  unsigned* bar = (unsigned*)(hbp + 2 * HB_STRIDE);  // 2048 u32

  hipMemsetAsync(bar, 0, 2048 * sizeof(unsigned), stream);
  init_h<<<dim3(HB_STRIDE / 256), dim3(256), 0, stream>>>(mem, hbp);
  pregemm<<<dim3(TT, 32), dim3(256), 0, stream>>>(X, Wih, bih, bhh, PG);
  lstm_persistent<<<dim3(64), dim3(512), 0, stream>>>(mem, Whh, PG, hbp, outmem, bar);
  transpose_out<<<dim3(TT, 8), dim3(256), 0, stream>>>(PG, out);
}